// Round 1
// baseline (943.274 us; speedup 1.0000x reference)
//
#include <hip/hip_runtime.h>

// Problem constants (match reference setup_inputs)
constexpr int NV = 100000;   // vertices
constexpr int NE = 1600000;  // directed edges
constexpr int NB = 64;       // graphs
constexpr int HD = 128;      // hidden
constexpr int DM = 256;      // out dim
#define EPSLN 1e-5f

// ---------- CSR build ----------
__global__ void k_deg(const int* __restrict__ ei, int* __restrict__ degi) {
    int e = blockIdx.x * 256 + threadIdx.x;
    if (e < NE) atomicAdd(&degi[ei[NE + e]], 1);  // dst = ei[1][e]
}

__global__ void k_dinv(const int* __restrict__ degi, float* __restrict__ dinv) {
    int v = blockIdx.x * 256 + threadIdx.x;
    if (v < NV) dinv[v] = rsqrtf((float)degi[v] + 1.0f);  // +1 self loop
}

// chunk = 1024 elements per block (256 thr x 4)
__global__ void k_scan_chunk(const int* __restrict__ deg, int* __restrict__ rowstart,
                             int* __restrict__ bsums) {
    __shared__ int sdata[256];
    int t = threadIdx.x;
    int base = blockIdx.x * 1024 + t * 4;
    int vals[4];
    int s = 0;
    #pragma unroll
    for (int j = 0; j < 4; ++j) {
        int idx = base + j;
        int d = (idx < NV) ? deg[idx] : 0;
        vals[j] = s; s += d;
    }
    sdata[t] = s; __syncthreads();
    for (int off = 1; off < 256; off <<= 1) {
        int v = sdata[t];
        int add = (t >= off) ? sdata[t - off] : 0;
        __syncthreads();
        sdata[t] = v + add;
        __syncthreads();
    }
    int excl = (t == 0) ? 0 : sdata[t - 1];
    #pragma unroll
    for (int j = 0; j < 4; ++j) {
        int idx = base + j;
        if (idx < NV) rowstart[idx] = excl + vals[j];
    }
    if (t == 0) bsums[blockIdx.x] = sdata[255];
}

__global__ void k_scan_sums(int* bsums, int nchunks) {
    if (threadIdx.x == 0 && blockIdx.x == 0) {
        int run = 0;
        for (int i = 0; i < nchunks; ++i) { int v = bsums[i]; bsums[i] = run; run += v; }
    }
}

__global__ void k_scan_add(int* __restrict__ rowstart, const int* __restrict__ bsums) {
    int i = blockIdx.x * 256 + threadIdx.x;
    if (i < NV) rowstart[i] += bsums[i >> 10];
}

__global__ void k_fill(const int* __restrict__ ei, const int* __restrict__ rowstart,
                       int* __restrict__ cursor, int* __restrict__ csr_src) {
    int e = blockIdx.x * 256 + threadIdx.x;
    if (e >= NE) return;
    int s = ei[e];
    int d = ei[NE + e];
    int p = atomicAdd(&cursor[d], 1);
    csr_src[rowstart[d] + p] = s;
}

// ---------- input linear: X = vertices @ W_in + b_in ----------
__global__ void k_in(const float* __restrict__ verts, const float* __restrict__ Win,
                     const float* __restrict__ bin, float* __restrict__ X) {
    int idx = blockIdx.x * 256 + threadIdx.x;
    if (idx >= NV * HD) return;
    int v = idx >> 7, c = idx & 127;
    float a = verts[v * 3 + 0], b = verts[v * 3 + 1], d = verts[v * 3 + 2];
    X[idx] = bin[c] + a * Win[c] + b * Win[128 + c] + d * Win[256 + c];
}

// ---------- H = X @ W  (f32, 64 rows/block, 4x4 register blocking) ----------
__global__ __launch_bounds__(512) void k_gemm128(const float* __restrict__ X,
                                                 const float* __restrict__ W,
                                                 float* __restrict__ H) {
    __shared__ float Ws[128 * 128];     // 64 KB
    __shared__ float Xs[128][65];       // transposed [k][row], padded
    int t = threadIdx.x;
    int row0 = blockIdx.x * 64;
    {
        const float4* Wv = (const float4*)W;
        float4* Wd = (float4*)Ws;
        #pragma unroll
        for (int i = 0; i < 8; ++i) Wd[t + i * 512] = Wv[t + i * 512];
    }
    {
        // 64 rows x 32 float4 along k = 2048 float4, 4 per thread
        #pragma unroll
        for (int i = 0; i < 4; ++i) {
            int idx = t + i * 512;
            int r = idx >> 5;       // row in tile
            int kq = idx & 31;      // k/4
            int row = row0 + r;
            float4 val = make_float4(0.f, 0.f, 0.f, 0.f);
            if (row < NV) val = *(const float4*)(X + (size_t)row * HD + kq * 4);
            Xs[kq * 4 + 0][r] = val.x;
            Xs[kq * 4 + 1][r] = val.y;
            Xs[kq * 4 + 2][r] = val.z;
            Xs[kq * 4 + 3][r] = val.w;
        }
    }
    __syncthreads();
    int tx = t & 31;       // col/4
    int ty = t >> 5;       // row/4 (0..15)
    float acc[4][4] = {};
    #pragma unroll 8
    for (int k = 0; k < 128; ++k) {
        float4 w4 = *(const float4*)&Ws[k * 128 + tx * 4];
        float xr[4];
        #pragma unroll
        for (int j = 0; j < 4; ++j) xr[j] = Xs[k][ty * 4 + j];
        #pragma unroll
        for (int j = 0; j < 4; ++j) {
            acc[j][0] = fmaf(xr[j], w4.x, acc[j][0]);
            acc[j][1] = fmaf(xr[j], w4.y, acc[j][1]);
            acc[j][2] = fmaf(xr[j], w4.z, acc[j][2]);
            acc[j][3] = fmaf(xr[j], w4.w, acc[j][3]);
        }
    }
    #pragma unroll
    for (int j = 0; j < 4; ++j) {
        int row = row0 + ty * 4 + j;
        if (row < NV)
            *(float4*)(H + (size_t)row * HD + tx * 4) =
                make_float4(acc[j][0], acc[j][1], acc[j][2], acc[j][3]);
    }
}

// ---------- aggregate: one wave per dst vertex, fused self-loop+bias+relu ----------
__global__ __launch_bounds__(256) void k_agg(const float* __restrict__ H,
                                             const float* __restrict__ dinv,
                                             const int* __restrict__ rowstart,
                                             const int* __restrict__ degi,
                                             const int* __restrict__ csr_src,
                                             const float* __restrict__ bias,
                                             float* __restrict__ Xo) {
    int gtid = blockIdx.x * 256 + threadIdx.x;
    int v = gtid >> 6;
    int lane = gtid & 63;
    if (v >= NV) return;
    float di = dinv[v];
    int rs = rowstart[v], len = degi[v];
    float2 hv = *(const float2*)(H + (size_t)v * HD + lane * 2);
    float sc = di * di;
    float a0 = hv.x * sc, a1 = hv.y * sc;
    int i = 0;
    for (; i + 1 < len; i += 2) {
        int s0 = csr_src[rs + i], s1 = csr_src[rs + i + 1];
        float w0 = dinv[s0] * di, w1 = dinv[s1] * di;
        float2 h0 = *(const float2*)(H + (size_t)s0 * HD + lane * 2);
        float2 h1 = *(const float2*)(H + (size_t)s1 * HD + lane * 2);
        a0 = fmaf(h0.x, w0, a0); a0 = fmaf(h1.x, w1, a0);
        a1 = fmaf(h0.y, w0, a1); a1 = fmaf(h1.y, w1, a1);
    }
    if (i < len) {
        int s0 = csr_src[rs + i];
        float w0 = dinv[s0] * di;
        float2 h0 = *(const float2*)(H + (size_t)s0 * HD + lane * 2);
        a0 = fmaf(h0.x, w0, a0);
        a1 = fmaf(h0.y, w0, a1);
    }
    float o0 = fmaxf(a0 + bias[lane * 2 + 0], 0.f);
    float o1 = fmaxf(a1 + bias[lane * 2 + 1], 0.f);
    *(float2*)(Xo + (size_t)v * HD + lane * 2) = make_float2(o0, o1);
}

// ---------- mean pool: run-length accumulate (batch is sorted) ----------
__global__ __launch_bounds__(128) void k_pool(const float* __restrict__ X,
                                              const int* __restrict__ batch,
                                              float* __restrict__ pool,
                                              int* __restrict__ cnt) {
    int t = threadIdx.x;
    int v0 = blockIdx.x * 512;
    if (v0 >= NV) return;
    int vend = min(v0 + 512, NV);
    int cur = batch[v0];
    float sum = 0.f;
    int c = 0;
    for (int v = v0; v < vend; ++v) {
        int bb = batch[v];
        if (bb != cur) {
            atomicAdd(&pool[cur * HD + t], sum);
            if (t == 0) atomicAdd(&cnt[cur], c);
            sum = 0.f; c = 0; cur = bb;
        }
        sum += X[(size_t)v * HD + t];
        ++c;
    }
    atomicAdd(&pool[cur * HD + t], sum);
    if (t == 0) atomicAdd(&cnt[cur], c);
}

// ---------- final linear + layernorm, one block per graph ----------
__global__ __launch_bounds__(256) void k_out(const float* __restrict__ pool,
                                             const int* __restrict__ cnt,
                                             const float* __restrict__ Wout,
                                             const float* __restrict__ bout,
                                             const float* __restrict__ gamma,
                                             const float* __restrict__ beta,
                                             float* __restrict__ out) {
    __shared__ float ps[HD];
    __shared__ float red[DM];
    int g = blockIdx.x, t = threadIdx.x;
    if (t < HD) {
        float cn = fmaxf((float)cnt[g], 1.0f);
        ps[t] = pool[g * HD + t] / cn;
    }
    __syncthreads();
    float acc = bout[t];
    #pragma unroll 8
    for (int k = 0; k < HD; ++k) acc = fmaf(ps[k], Wout[k * DM + t], acc);
    red[t] = acc; __syncthreads();
    for (int s2 = 128; s2 > 0; s2 >>= 1) {
        if (t < s2) red[t] += red[t + s2];
        __syncthreads();
    }
    float mu = red[0] * (1.0f / DM);
    __syncthreads();
    float d = acc - mu;
    red[t] = d * d; __syncthreads();
    for (int s2 = 128; s2 > 0; s2 >>= 1) {
        if (t < s2) red[t] += red[t + s2];
        __syncthreads();
    }
    float var = red[0] * (1.0f / DM);
    out[g * DM + t] = d * rsqrtf(var + EPSLN) * gamma[t] + beta[t];
}

extern "C" void kernel_launch(void* const* d_in, const int* in_sizes, int n_in,
                              void* d_out, int out_size, void* d_ws, size_t ws_size,
                              hipStream_t stream) {
    const float* verts = (const float*)d_in[0];
    const int*   ei    = (const int*)d_in[1];
    const int*   batch = (const int*)d_in[2];
    const float* Win   = (const float*)d_in[3];
    const float* bin   = (const float*)d_in[4];
    const float* W1    = (const float*)d_in[5];
    const float* b1    = (const float*)d_in[6];
    const float* W2    = (const float*)d_in[7];
    const float* b2    = (const float*)d_in[8];
    const float* W3    = (const float*)d_in[9];
    const float* b3    = (const float*)d_in[10];
    const float* Wout  = (const float*)d_in[11];
    const float* bout  = (const float*)d_in[12];
    const float* gamma = (const float*)d_in[13];
    const float* beta  = (const float*)d_in[14];
    float* out = (float*)d_out;

    char* wp = (char*)d_ws;
    auto alloc = [&](size_t bytes) -> char* {
        char* p = wp;
        wp += (bytes + 255) & ~(size_t)255;
        return p;
    };
    float* X        = (float*)alloc((size_t)NV * HD * 4);
    float* H        = (float*)alloc((size_t)NV * HD * 4);
    int*   degi     = (int*)alloc((size_t)NV * 4);
    float* dinv     = (float*)alloc((size_t)NV * 4);
    int*   rowstart = (int*)alloc((size_t)NV * 4);
    int*   cursor   = (int*)alloc((size_t)NV * 4);
    int*   csr      = (int*)alloc((size_t)NE * 4);
    float* pool     = (float*)alloc((size_t)NB * HD * 4);
    int*   cnt      = (int*)alloc((size_t)NB * 4);
    int*   bsums    = (int*)alloc(1024 * 4);

    hipMemsetAsync(degi,   0, (size_t)NV * 4, stream);
    hipMemsetAsync(cursor, 0, (size_t)NV * 4, stream);
    hipMemsetAsync(pool,   0, (size_t)NB * HD * 4, stream);
    hipMemsetAsync(cnt,    0, (size_t)NB * 4, stream);

    k_deg<<<(NE + 255) / 256, 256, 0, stream>>>(ei, degi);
    k_dinv<<<(NV + 255) / 256, 256, 0, stream>>>(degi, dinv);
    int nch = (NV + 1023) / 1024;
    k_scan_chunk<<<nch, 256, 0, stream>>>(degi, rowstart, bsums);
    k_scan_sums<<<1, 64, 0, stream>>>(bsums, nch);
    k_scan_add<<<(NV + 255) / 256, 256, 0, stream>>>(rowstart, bsums);
    k_fill<<<(NE + 255) / 256, 256, 0, stream>>>(ei, rowstart, cursor, csr);

    k_in<<<((size_t)NV * HD + 255) / 256, 256, 0, stream>>>(verts, Win, bin, X);

    const float* Wl[3] = {W1, W2, W3};
    const float* bl[3] = {b1, b2, b3};
    for (int l = 0; l < 3; ++l) {
        k_gemm128<<<(NV + 63) / 64, 512, 0, stream>>>(X, Wl[l], H);
        k_agg<<<((size_t)NV * 64 + 255) / 256, 256, 0, stream>>>(H, dinv, rowstart, degi, csr, bl[l], X);
    }

    k_pool<<<(NV + 511) / 512, 128, 0, stream>>>(X, batch, pool, cnt);
    k_out<<<NB, 256, 0, stream>>>(pool, cnt, Wout, bout, gamma, beta, out);
}

// Round 2
// 829.724 us; speedup vs baseline: 1.1369x; 1.1369x over previous
//
#include <hip/hip_runtime.h>

// Problem constants (match reference setup_inputs)
constexpr int NV = 100000;   // vertices
constexpr int NE = 1600000;  // directed edges
constexpr int NB = 64;       // graphs
constexpr int HD = 128;      // hidden
constexpr int DM = 256;      // out dim
#define EPSLN 1e-5f

// ---------- CSR build ----------
__global__ void k_deg(const int* __restrict__ ei, int* __restrict__ degi) {
    int e = blockIdx.x * 256 + threadIdx.x;
    if (e < NE) atomicAdd(&degi[ei[NE + e]], 1);  // dst = ei[1][e]
}

__global__ void k_dinv(const int* __restrict__ degi, float* __restrict__ dinv) {
    int v = blockIdx.x * 256 + threadIdx.x;
    if (v < NV) dinv[v] = rsqrtf((float)degi[v] + 1.0f);  // +1 self loop
}

// chunk = 1024 elements per block (256 thr x 4)
__global__ void k_scan_chunk(const int* __restrict__ deg, int* __restrict__ rowstart,
                             int* __restrict__ bsums) {
    __shared__ int sdata[256];
    int t = threadIdx.x;
    int base = blockIdx.x * 1024 + t * 4;
    int vals[4];
    int s = 0;
    #pragma unroll
    for (int j = 0; j < 4; ++j) {
        int idx = base + j;
        int d = (idx < NV) ? deg[idx] : 0;
        vals[j] = s; s += d;
    }
    sdata[t] = s; __syncthreads();
    for (int off = 1; off < 256; off <<= 1) {
        int v = sdata[t];
        int add = (t >= off) ? sdata[t - off] : 0;
        __syncthreads();
        sdata[t] = v + add;
        __syncthreads();
    }
    int excl = (t == 0) ? 0 : sdata[t - 1];
    #pragma unroll
    for (int j = 0; j < 4; ++j) {
        int idx = base + j;
        if (idx < NV) rowstart[idx] = excl + vals[j];
    }
    if (t == 0) bsums[blockIdx.x] = sdata[255];
}

__global__ void k_scan_sums(int* bsums, int nchunks) {
    if (threadIdx.x == 0 && blockIdx.x == 0) {
        int run = 0;
        for (int i = 0; i < nchunks; ++i) { int v = bsums[i]; bsums[i] = run; run += v; }
    }
}

__global__ void k_scan_add(int* __restrict__ rowstart, const int* __restrict__ bsums) {
    int i = blockIdx.x * 256 + threadIdx.x;
    if (i < NV) rowstart[i] += bsums[i >> 10];
}

__global__ void k_fill(const int* __restrict__ ei, const int* __restrict__ rowstart,
                       int* __restrict__ cursor, int* __restrict__ csr_src) {
    int e = blockIdx.x * 256 + threadIdx.x;
    if (e >= NE) return;
    int s = ei[e];
    int d = ei[NE + e];
    int p = atomicAdd(&cursor[d], 1);
    csr_src[rowstart[d] + p] = s;
}

// ---------- input linear: X = vertices @ W_in + b_in ----------
__global__ void k_in(const float* __restrict__ verts, const float* __restrict__ Win,
                     const float* __restrict__ bin, float* __restrict__ X) {
    int idx = blockIdx.x * 256 + threadIdx.x;
    if (idx >= NV * HD) return;
    int v = idx >> 7, c = idx & 127;
    float a = verts[v * 3 + 0], b = verts[v * 3 + 1], d = verts[v * 3 + 2];
    X[idx] = bin[c] + a * Win[c] + b * Win[128 + c] + d * Win[256 + c];
}

// ---------- H = X @ W  (f32, 64 rows/block, 4x4 register blocking) ----------
__global__ __launch_bounds__(512) void k_gemm128(const float* __restrict__ X,
                                                 const float* __restrict__ W,
                                                 float* __restrict__ H) {
    __shared__ float Ws[128 * 128];     // 64 KB
    __shared__ float Xs[128][65];       // transposed [k][row], padded
    int t = threadIdx.x;
    int row0 = blockIdx.x * 64;
    {
        const float4* Wv = (const float4*)W;
        float4* Wd = (float4*)Ws;
        #pragma unroll
        for (int i = 0; i < 8; ++i) Wd[t + i * 512] = Wv[t + i * 512];
    }
    {
        // 64 rows x 32 float4 along k = 2048 float4, 4 per thread
        #pragma unroll
        for (int i = 0; i < 4; ++i) {
            int idx = t + i * 512;
            int r = idx >> 5;       // row in tile
            int kq = idx & 31;      // k/4
            int row = row0 + r;
            float4 val = make_float4(0.f, 0.f, 0.f, 0.f);
            if (row < NV) val = *(const float4*)(X + (size_t)row * HD + kq * 4);
            Xs[kq * 4 + 0][r] = val.x;
            Xs[kq * 4 + 1][r] = val.y;
            Xs[kq * 4 + 2][r] = val.z;
            Xs[kq * 4 + 3][r] = val.w;
        }
    }
    __syncthreads();
    int tx = t & 31;       // col/4
    int ty = t >> 5;       // row/4 (0..15)
    float acc[4][4] = {};
    #pragma unroll 8
    for (int k = 0; k < 128; ++k) {
        float4 w4 = *(const float4*)&Ws[k * 128 + tx * 4];
        float xr[4];
        #pragma unroll
        for (int j = 0; j < 4; ++j) xr[j] = Xs[k][ty * 4 + j];
        #pragma unroll
        for (int j = 0; j < 4; ++j) {
            acc[j][0] = fmaf(xr[j], w4.x, acc[j][0]);
            acc[j][1] = fmaf(xr[j], w4.y, acc[j][1]);
            acc[j][2] = fmaf(xr[j], w4.z, acc[j][2]);
            acc[j][3] = fmaf(xr[j], w4.w, acc[j][3]);
        }
    }
    #pragma unroll
    for (int j = 0; j < 4; ++j) {
        int row = row0 + ty * 4 + j;
        if (row < NV)
            *(float4*)(H + (size_t)row * HD + tx * 4) =
                make_float4(acc[j][0], acc[j][1], acc[j][2], acc[j][3]);
    }
}

// ---------- aggregate: one wave per dst vertex, fused self-loop+bias+relu ----------
__global__ __launch_bounds__(256) void k_agg(const float* __restrict__ H,
                                             const float* __restrict__ dinv,
                                             const int* __restrict__ rowstart,
                                             const int* __restrict__ degi,
                                             const int* __restrict__ csr_src,
                                             const float* __restrict__ bias,
                                             float* __restrict__ Xo) {
    int gtid = blockIdx.x * 256 + threadIdx.x;
    int v = gtid >> 6;
    int lane = gtid & 63;
    if (v >= NV) return;
    float di = dinv[v];
    int rs = rowstart[v], len = degi[v];
    float2 hv = *(const float2*)(H + (size_t)v * HD + lane * 2);
    float sc = di * di;
    float a0 = hv.x * sc, a1 = hv.y * sc;
    int i = 0;
    for (; i + 1 < len; i += 2) {
        int s0 = csr_src[rs + i], s1 = csr_src[rs + i + 1];
        float w0 = dinv[s0] * di, w1 = dinv[s1] * di;
        float2 h0 = *(const float2*)(H + (size_t)s0 * HD + lane * 2);
        float2 h1 = *(const float2*)(H + (size_t)s1 * HD + lane * 2);
        a0 = fmaf(h0.x, w0, a0); a0 = fmaf(h1.x, w1, a0);
        a1 = fmaf(h0.y, w0, a1); a1 = fmaf(h1.y, w1, a1);
    }
    if (i < len) {
        int s0 = csr_src[rs + i];
        float w0 = dinv[s0] * di;
        float2 h0 = *(const float2*)(H + (size_t)s0 * HD + lane * 2);
        a0 = fmaf(h0.x, w0, a0);
        a1 = fmaf(h0.y, w0, a1);
    }
    float o0 = fmaxf(a0 + bias[lane * 2 + 0], 0.f);
    float o1 = fmaxf(a1 + bias[lane * 2 + 1], 0.f);
    *(float2*)(Xo + (size_t)v * HD + lane * 2) = make_float2(o0, o1);
}

// ---------- mean pool: 2048 blocks x 256 thr, register run-length accumulate ----------
__global__ __launch_bounds__(256) void k_pool(const float* __restrict__ X,
                                              const int* __restrict__ batch,
                                              float* __restrict__ pool,
                                              int* __restrict__ cnt) {
    constexpr int NCHUNK = 2048;
    constexpr int CHUNK = (NV + NCHUNK - 1) / NCHUNK;  // 49
    int c = threadIdx.x & 127;   // column
    int r = threadIdx.x >> 7;    // 0..1 vertex-row offset
    int v0 = blockIdx.x * CHUNK;
    if (v0 >= NV) return;
    int vend = min(v0 + CHUNK, NV);
    int cur = -1;
    float sum = 0.f;
    for (int v = v0 + r; v < vend; v += 2) {
        int bb = batch[v];
        if (bb != cur) {
            if (cur >= 0) atomicAdd(&pool[cur * HD + c], sum);
            cur = bb; sum = 0.f;
        }
        sum += X[(size_t)v * HD + c];
    }
    if (cur >= 0) atomicAdd(&pool[cur * HD + c], sum);
    if (threadIdx.x == 0) {
        int prev = batch[v0]; int c0 = 0;
        for (int v = v0; v < vend; ++v) {
            int bb = batch[v];
            if (bb != prev) { atomicAdd(&cnt[prev], c0); prev = bb; c0 = 0; }
            ++c0;
        }
        atomicAdd(&cnt[prev], c0);
    }
}

// ---------- final linear + layernorm, one block per graph ----------
__global__ __launch_bounds__(256) void k_out(const float* __restrict__ pool,
                                             const int* __restrict__ cnt,
                                             const float* __restrict__ Wout,
                                             const float* __restrict__ bout,
                                             const float* __restrict__ gamma,
                                             const float* __restrict__ beta,
                                             float* __restrict__ out) {
    __shared__ float ps[HD];
    __shared__ float red[DM];
    int g = blockIdx.x, t = threadIdx.x;
    if (t < HD) {
        float cn = fmaxf((float)cnt[g], 1.0f);
        ps[t] = pool[g * HD + t] / cn;
    }
    __syncthreads();
    float acc = bout[t];
    #pragma unroll 8
    for (int k = 0; k < HD; ++k) acc = fmaf(ps[k], Wout[k * DM + t], acc);
    red[t] = acc; __syncthreads();
    for (int s2 = 128; s2 > 0; s2 >>= 1) {
        if (t < s2) red[t] += red[t + s2];
        __syncthreads();
    }
    float mu = red[0] * (1.0f / DM);
    __syncthreads();
    float d = acc - mu;
    red[t] = d * d; __syncthreads();
    for (int s2 = 128; s2 > 0; s2 >>= 1) {
        if (t < s2) red[t] += red[t + s2];
        __syncthreads();
    }
    float var = red[0] * (1.0f / DM);
    out[g * DM + t] = d * rsqrtf(var + EPSLN) * gamma[t] + beta[t];
}

extern "C" void kernel_launch(void* const* d_in, const int* in_sizes, int n_in,
                              void* d_out, int out_size, void* d_ws, size_t ws_size,
                              hipStream_t stream) {
    const float* verts = (const float*)d_in[0];
    const int*   ei    = (const int*)d_in[1];
    const int*   batch = (const int*)d_in[2];
    const float* Win   = (const float*)d_in[3];
    const float* bin   = (const float*)d_in[4];
    const float* W1    = (const float*)d_in[5];
    const float* b1    = (const float*)d_in[6];
    const float* W2    = (const float*)d_in[7];
    const float* b2    = (const float*)d_in[8];
    const float* W3    = (const float*)d_in[9];
    const float* b3    = (const float*)d_in[10];
    const float* Wout  = (const float*)d_in[11];
    const float* bout  = (const float*)d_in[12];
    const float* gamma = (const float*)d_in[13];
    const float* beta  = (const float*)d_in[14];
    float* out = (float*)d_out;

    char* wp = (char*)d_ws;
    auto alloc = [&](size_t bytes) -> char* {
        char* p = wp;
        wp += (bytes + 255) & ~(size_t)255;
        return p;
    };
    float* X        = (float*)alloc((size_t)NV * HD * 4);
    float* H        = (float*)alloc((size_t)NV * HD * 4);
    int*   degi     = (int*)alloc((size_t)NV * 4);
    float* dinv     = (float*)alloc((size_t)NV * 4);
    int*   rowstart = (int*)alloc((size_t)NV * 4);
    int*   cursor   = (int*)alloc((size_t)NV * 4);
    int*   csr      = (int*)alloc((size_t)NE * 4);
    float* pool     = (float*)alloc((size_t)NB * HD * 4);
    int*   cnt      = (int*)alloc((size_t)NB * 4);
    int*   bsums    = (int*)alloc(1024 * 4);

    hipMemsetAsync(degi,   0, (size_t)NV * 4, stream);
    hipMemsetAsync(cursor, 0, (size_t)NV * 4, stream);
    hipMemsetAsync(pool,   0, (size_t)NB * HD * 4, stream);
    hipMemsetAsync(cnt,    0, (size_t)NB * 4, stream);

    k_deg<<<(NE + 255) / 256, 256, 0, stream>>>(ei, degi);
    k_dinv<<<(NV + 255) / 256, 256, 0, stream>>>(degi, dinv);
    int nch = (NV + 1023) / 1024;
    k_scan_chunk<<<nch, 256, 0, stream>>>(degi, rowstart, bsums);
    k_scan_sums<<<1, 64, 0, stream>>>(bsums, nch);
    k_scan_add<<<(NV + 255) / 256, 256, 0, stream>>>(rowstart, bsums);
    k_fill<<<(NE + 255) / 256, 256, 0, stream>>>(ei, rowstart, cursor, csr);

    k_in<<<((size_t)NV * HD + 255) / 256, 256, 0, stream>>>(verts, Win, bin, X);

    const float* Wl[3] = {W1, W2, W3};
    const float* bl[3] = {b1, b2, b3};
    for (int l = 0; l < 3; ++l) {
        k_gemm128<<<(NV + 63) / 64, 512, 0, stream>>>(X, Wl[l], H);
        k_agg<<<((size_t)NV * 64 + 255) / 256, 256, 0, stream>>>(H, dinv, rowstart, degi, csr, bl[l], X);
    }

    k_pool<<<2048, 256, 0, stream>>>(X, batch, pool, cnt);
    k_out<<<NB, 256, 0, stream>>>(pool, cnt, Wout, bout, gamma, beta, out);
}

// Round 3
// 657.845 us; speedup vs baseline: 1.4339x; 1.2613x over previous
//
#include <hip/hip_runtime.h>

// Problem constants (match reference setup_inputs)
constexpr int NV = 100000;   // vertices
constexpr int NE = 1600000;  // directed edges
constexpr int NB = 64;       // graphs
constexpr int HD = 128;      // hidden
constexpr int DM = 256;      // out dim
#define EPSLN 1e-5f

typedef short bf16x8 __attribute__((ext_vector_type(8)));
typedef float f32x4 __attribute__((ext_vector_type(4)));

__device__ inline unsigned short f2b(float f) {
    union { float f; unsigned u; } x; x.f = f;
    unsigned r = x.u + 0x7FFF + ((x.u >> 16) & 1);
    return (unsigned short)(r >> 16);
}
__device__ inline float b2f(unsigned short h) {
    union { unsigned u; float f; } x; x.u = (unsigned)h << 16;
    return x.f;
}

// ---------- CSR build ----------
__global__ void k_deg(const int* __restrict__ ei, int* __restrict__ degi) {
    int e = blockIdx.x * 256 + threadIdx.x;
    if (e < NE) atomicAdd(&degi[ei[NE + e]], 1);  // dst = ei[1][e]
}

__global__ void k_dinv(const int* __restrict__ degi, float* __restrict__ dinv) {
    int v = blockIdx.x * 256 + threadIdx.x;
    if (v < NV) dinv[v] = rsqrtf((float)degi[v] + 1.0f);  // +1 self loop
}

// chunk = 1024 elements per block (256 thr x 4)
__global__ void k_scan_chunk(const int* __restrict__ deg, int* __restrict__ rowstart,
                             int* __restrict__ bsums) {
    __shared__ int sdata[256];
    int t = threadIdx.x;
    int base = blockIdx.x * 1024 + t * 4;
    int vals[4];
    int s = 0;
    #pragma unroll
    for (int j = 0; j < 4; ++j) {
        int idx = base + j;
        int d = (idx < NV) ? deg[idx] : 0;
        vals[j] = s; s += d;
    }
    sdata[t] = s; __syncthreads();
    for (int off = 1; off < 256; off <<= 1) {
        int v = sdata[t];
        int add = (t >= off) ? sdata[t - off] : 0;
        __syncthreads();
        sdata[t] = v + add;
        __syncthreads();
    }
    int excl = (t == 0) ? 0 : sdata[t - 1];
    #pragma unroll
    for (int j = 0; j < 4; ++j) {
        int idx = base + j;
        if (idx < NV) rowstart[idx] = excl + vals[j];
    }
    if (t == 0) bsums[blockIdx.x] = sdata[255];
}

__global__ void k_scan_sums(int* bsums, int nchunks) {
    if (threadIdx.x == 0 && blockIdx.x == 0) {
        int run = 0;
        for (int i = 0; i < nchunks; ++i) { int v = bsums[i]; bsums[i] = run; run += v; }
    }
}

__global__ void k_scan_add(int* __restrict__ rowstart, const int* __restrict__ bsums) {
    int i = blockIdx.x * 256 + threadIdx.x;
    if (i < NV) rowstart[i] += bsums[i >> 10];
}

__global__ void k_fill(const int* __restrict__ ei, const int* __restrict__ rowstart,
                       int* __restrict__ cursor, int* __restrict__ csr_src) {
    int e = blockIdx.x * 256 + threadIdx.x;
    if (e >= NE) return;
    int s = ei[e];
    int d = ei[NE + e];
    int p = atomicAdd(&cursor[d], 1);
    csr_src[rowstart[d] + p] = s;
}

// ---------- input linear: Xb = bf16(vertices @ W_in + b_in) ----------
__global__ void k_in(const float* __restrict__ verts, const float* __restrict__ Win,
                     const float* __restrict__ bin, unsigned short* __restrict__ Xb) {
    int idx = blockIdx.x * 256 + threadIdx.x;
    if (idx >= NV * HD) return;
    int v = idx >> 7, c = idx & 127;
    float a = verts[v * 3 + 0], b = verts[v * 3 + 1], d = verts[v * 3 + 2];
    Xb[idx] = f2b(bin[c] + a * Win[c] + b * Win[128 + c] + d * Win[256 + c]);
}

// ---------- W [k][n] f32 -> Wt [n][k] bf16 ----------
__global__ void k_wt(const float* __restrict__ W, unsigned short* __restrict__ Wt) {
    int idx = blockIdx.x * 256 + threadIdx.x;
    if (idx >= HD * HD) return;
    int n = idx >> 7, k = idx & 127;
    Wt[n * HD + k] = f2b(W[k * HD + n]);
}

// ---------- H = X @ W  via MFMA bf16: 4 waves/block, 64 rows/block ----------
__global__ __launch_bounds__(256) void k_gemm_mfma(const unsigned short* __restrict__ Xb,
                                                   const unsigned short* __restrict__ Wt,
                                                   unsigned short* __restrict__ Hb) {
    int wave = threadIdx.x >> 6;
    int lane = threadIdx.x & 63;
    int r = lane & 15;
    int g = lane >> 4;                     // 0..3
    int row0 = blockIdx.x * 64 + wave * 16;
    int arow = row0 + r;
    bool valid = arow < NV;

    bf16x8 afrag[4];
    const unsigned short* xp = Xb + (size_t)arow * HD + g * 8;
    #pragma unroll
    for (int ks = 0; ks < 4; ++ks) {
        if (valid) afrag[ks] = *(const bf16x8*)(xp + ks * 32);
        else       afrag[ks] = bf16x8{0, 0, 0, 0, 0, 0, 0, 0};
    }

    #pragma unroll
    for (int nt = 0; nt < 8; ++nt) {
        f32x4 acc = {0.f, 0.f, 0.f, 0.f};
        const unsigned short* wp = Wt + (size_t)(nt * 16 + r) * HD + g * 8;
        #pragma unroll
        for (int ks = 0; ks < 4; ++ks) {
            bf16x8 bfrag = *(const bf16x8*)(wp + ks * 32);
            acc = __builtin_amdgcn_mfma_f32_16x16x32_bf16(afrag[ks], bfrag, acc, 0, 0, 0);
        }
        #pragma unroll
        for (int j = 0; j < 4; ++j) {
            int row = row0 + g * 4 + j;   // C/D: col = lane&15, row = (lane>>4)*4 + reg
            if (row < NV)
                Hb[(size_t)row * HD + nt * 16 + r] = f2b(acc[j]);
        }
    }
}

// ---------- aggregate: one wave per dst vertex, bf16 gather, f32 accum ----------
__global__ __launch_bounds__(256) void k_agg(const unsigned short* __restrict__ H,
                                             const float* __restrict__ dinv,
                                             const int* __restrict__ rowstart,
                                             const int* __restrict__ degi,
                                             const int* __restrict__ csr_src,
                                             const float* __restrict__ bias,
                                             unsigned short* __restrict__ Xo) {
    int gtid = blockIdx.x * 256 + threadIdx.x;
    int v = gtid >> 6;
    int lane = gtid & 63;
    if (v >= NV) return;
    float di = dinv[v];
    int rs = rowstart[v], len = degi[v];
    ushort2 hv = *(const ushort2*)(H + (size_t)v * HD + lane * 2);
    float sc = di * di;
    float a0 = b2f(hv.x) * sc, a1 = b2f(hv.y) * sc;
    int i = 0;
    for (; i + 1 < len; i += 2) {
        int s0 = csr_src[rs + i], s1 = csr_src[rs + i + 1];
        float w0 = dinv[s0] * di, w1 = dinv[s1] * di;
        ushort2 h0 = *(const ushort2*)(H + (size_t)s0 * HD + lane * 2);
        ushort2 h1 = *(const ushort2*)(H + (size_t)s1 * HD + lane * 2);
        a0 = fmaf(b2f(h0.x), w0, a0); a0 = fmaf(b2f(h1.x), w1, a0);
        a1 = fmaf(b2f(h0.y), w0, a1); a1 = fmaf(b2f(h1.y), w1, a1);
    }
    if (i < len) {
        int s0 = csr_src[rs + i];
        float w0 = dinv[s0] * di;
        ushort2 h0 = *(const ushort2*)(H + (size_t)s0 * HD + lane * 2);
        a0 = fmaf(b2f(h0.x), w0, a0);
        a1 = fmaf(b2f(h0.y), w0, a1);
    }
    float o0 = fmaxf(a0 + bias[lane * 2 + 0], 0.f);
    float o1 = fmaxf(a1 + bias[lane * 2 + 1], 0.f);
    ushort2 ov; ov.x = f2b(o0); ov.y = f2b(o1);
    *(ushort2*)(Xo + (size_t)v * HD + lane * 2) = ov;
}

// ---------- mean pool: 2048 blocks x 256 thr, register run-length accumulate ----------
__global__ __launch_bounds__(256) void k_pool(const unsigned short* __restrict__ X,
                                              const int* __restrict__ batch,
                                              float* __restrict__ pool,
                                              int* __restrict__ cnt) {
    constexpr int NCHUNK = 2048;
    constexpr int CHUNK = (NV + NCHUNK - 1) / NCHUNK;  // 49
    int c = threadIdx.x & 127;   // column
    int r = threadIdx.x >> 7;    // 0..1 vertex-row offset
    int v0 = blockIdx.x * CHUNK;
    if (v0 >= NV) return;
    int vend = min(v0 + CHUNK, NV);
    int cur = -1;
    float sum = 0.f;
    for (int v = v0 + r; v < vend; v += 2) {
        int bb = batch[v];
        if (bb != cur) {
            if (cur >= 0) atomicAdd(&pool[cur * HD + c], sum);
            cur = bb; sum = 0.f;
        }
        sum += b2f(X[(size_t)v * HD + c]);
    }
    if (cur >= 0) atomicAdd(&pool[cur * HD + c], sum);
    if (threadIdx.x == 0) {
        int prev = batch[v0]; int c0 = 0;
        for (int v = v0; v < vend; ++v) {
            int bb = batch[v];
            if (bb != prev) { atomicAdd(&cnt[prev], c0); prev = bb; c0 = 0; }
            ++c0;
        }
        atomicAdd(&cnt[prev], c0);
    }
}

// ---------- final linear + layernorm, one block per graph ----------
__global__ __launch_bounds__(256) void k_out(const float* __restrict__ pool,
                                             const int* __restrict__ cnt,
                                             const float* __restrict__ Wout,
                                             const float* __restrict__ bout,
                                             const float* __restrict__ gamma,
                                             const float* __restrict__ beta,
                                             float* __restrict__ out) {
    __shared__ float ps[HD];
    __shared__ float red[DM];
    int g = blockIdx.x, t = threadIdx.x;
    if (t < HD) {
        float cn = fmaxf((float)cnt[g], 1.0f);
        ps[t] = pool[g * HD + t] / cn;
    }
    __syncthreads();
    float acc = bout[t];
    #pragma unroll 8
    for (int k = 0; k < HD; ++k) acc = fmaf(ps[k], Wout[k * DM + t], acc);
    red[t] = acc; __syncthreads();
    for (int s2 = 128; s2 > 0; s2 >>= 1) {
        if (t < s2) red[t] += red[t + s2];
        __syncthreads();
    }
    float mu = red[0] * (1.0f / DM);
    __syncthreads();
    float d = acc - mu;
    red[t] = d * d; __syncthreads();
    for (int s2 = 128; s2 > 0; s2 >>= 1) {
        if (t < s2) red[t] += red[t + s2];
        __syncthreads();
    }
    float var = red[0] * (1.0f / DM);
    out[g * DM + t] = d * rsqrtf(var + EPSLN) * gamma[t] + beta[t];
}

extern "C" void kernel_launch(void* const* d_in, const int* in_sizes, int n_in,
                              void* d_out, int out_size, void* d_ws, size_t ws_size,
                              hipStream_t stream) {
    const float* verts = (const float*)d_in[0];
    const int*   ei    = (const int*)d_in[1];
    const int*   batch = (const int*)d_in[2];
    const float* Win   = (const float*)d_in[3];
    const float* bin   = (const float*)d_in[4];
    const float* W1    = (const float*)d_in[5];
    const float* b1    = (const float*)d_in[6];
    const float* W2    = (const float*)d_in[7];
    const float* b2    = (const float*)d_in[8];
    const float* W3    = (const float*)d_in[9];
    const float* b3    = (const float*)d_in[10];
    const float* Wout  = (const float*)d_in[11];
    const float* bout  = (const float*)d_in[12];
    const float* gamma = (const float*)d_in[13];
    const float* beta  = (const float*)d_in[14];
    float* out = (float*)d_out;

    char* wp = (char*)d_ws;
    auto alloc = [&](size_t bytes) -> char* {
        char* p = wp;
        wp += (bytes + 255) & ~(size_t)255;
        return p;
    };
    unsigned short* Xb  = (unsigned short*)alloc((size_t)NV * HD * 2);
    unsigned short* Hb  = (unsigned short*)alloc((size_t)NV * HD * 2);
    unsigned short* Wt  = (unsigned short*)alloc((size_t)HD * HD * 2);
    int*   degi     = (int*)alloc((size_t)NV * 4);
    float* dinv     = (float*)alloc((size_t)NV * 4);
    int*   rowstart = (int*)alloc((size_t)NV * 4);
    int*   cursor   = (int*)alloc((size_t)NV * 4);
    int*   csr      = (int*)alloc((size_t)NE * 4);
    float* pool     = (float*)alloc((size_t)NB * HD * 4);
    int*   cnt      = (int*)alloc((size_t)NB * 4);
    int*   bsums    = (int*)alloc(1024 * 4);

    hipMemsetAsync(degi,   0, (size_t)NV * 4, stream);
    hipMemsetAsync(cursor, 0, (size_t)NV * 4, stream);
    hipMemsetAsync(pool,   0, (size_t)NB * HD * 4, stream);
    hipMemsetAsync(cnt,    0, (size_t)NB * 4, stream);

    k_deg<<<(NE + 255) / 256, 256, 0, stream>>>(ei, degi);
    k_dinv<<<(NV + 255) / 256, 256, 0, stream>>>(degi, dinv);
    int nch = (NV + 1023) / 1024;
    k_scan_chunk<<<nch, 256, 0, stream>>>(degi, rowstart, bsums);
    k_scan_sums<<<1, 64, 0, stream>>>(bsums, nch);
    k_scan_add<<<(NV + 255) / 256, 256, 0, stream>>>(rowstart, bsums);
    k_fill<<<(NE + 255) / 256, 256, 0, stream>>>(ei, rowstart, cursor, csr);

    k_in<<<((size_t)NV * HD + 255) / 256, 256, 0, stream>>>(verts, Win, bin, Xb);

    const float* Wl[3] = {W1, W2, W3};
    const float* bl[3] = {b1, b2, b3};
    for (int l = 0; l < 3; ++l) {
        k_wt<<<(HD * HD + 255) / 256, 256, 0, stream>>>(Wl[l], Wt);
        k_gemm_mfma<<<(NV + 63) / 64, 256, 0, stream>>>(Xb, Wt, Hb);
        k_agg<<<((size_t)NV * 64 + 255) / 256, 256, 0, stream>>>(Hb, dinv, rowstart, degi, csr, bl[l], Xb);
    }

    k_pool<<<2048, 256, 0, stream>>>(Xb, batch, pool, cnt);
    k_out<<<NB, 256, 0, stream>>>(pool, cnt, Wout, bout, gamma, beta, out);
}

// Round 4
// 549.510 us; speedup vs baseline: 1.7166x; 1.1972x over previous
//
#include <hip/hip_runtime.h>

// Problem constants (match reference setup_inputs)
constexpr int NV = 100000;   // vertices
constexpr int NE = 1600000;  // directed edges
constexpr int NB = 64;       // graphs
constexpr int HD = 128;      // hidden
constexpr int DM = 256;      // out dim
#define EPSLN 1e-5f

// CSR bucketing
constexpr int DPB   = 512;                      // dsts per bucket
constexpr int NBUCK = (NV + DPB - 1) / DPB;     // 196
constexpr int EPB   = 4096;                     // edges per block (bucket kernels)
constexpr int NEB   = (NE + EPB - 1) / EPB;     // 391

typedef short bf16x8 __attribute__((ext_vector_type(8)));
typedef float f32x4 __attribute__((ext_vector_type(4)));

__device__ inline unsigned short f2b(float f) {
    union { float f; unsigned u; } x; x.f = f;
    unsigned r = x.u + 0x7FFF + ((x.u >> 16) & 1);
    return (unsigned short)(r >> 16);
}
__device__ inline float b2f(unsigned short h) {
    union { unsigned u; float f; } x; x.u = (unsigned)h << 16;
    return x.f;
}

// ---------- bucket histogram: count edges per dst-bucket ----------
__global__ __launch_bounds__(256) void k_bhist(const int* __restrict__ ei,
                                               int* __restrict__ bcount) {
    __shared__ int h[NBUCK];
    int t = threadIdx.x;
    for (int i = t; i < NBUCK; i += 256) h[i] = 0;
    __syncthreads();
    int base = blockIdx.x * EPB;
    #pragma unroll
    for (int j = 0; j < EPB / 256; ++j) {
        int idx = base + j * 256 + t;
        if (idx < NE) atomicAdd(&h[ei[NE + idx] >> 9], 1);
    }
    __syncthreads();
    for (int i = t; i < NBUCK; i += 256) if (h[i]) atomicAdd(&bcount[i], h[i]);
}

__global__ void k_bscan(const int* __restrict__ bcount, int* __restrict__ bstart,
                        int* __restrict__ bcursor) {
    if (threadIdx.x == 0 && blockIdx.x == 0) {
        int run = 0;
        for (int i = 0; i < NBUCK; ++i) { bstart[i] = run; bcursor[i] = run; run += bcount[i]; }
        bstart[NBUCK] = run;
    }
}

// ---------- scatter edges into bucket regions (coalesced runs) ----------
__global__ __launch_bounds__(256) void k_bscatter(const int* __restrict__ ei,
                                                  int* __restrict__ bcursor,
                                                  int2* __restrict__ ebuf) {
    __shared__ int h[NBUCK];
    __shared__ int lbase[NBUCK];
    int t = threadIdx.x;
    for (int i = t; i < NBUCK; i += 256) h[i] = 0;
    __syncthreads();
    int base = blockIdx.x * EPB;
    int s[16], d[16], rk[16];
    #pragma unroll
    for (int j = 0; j < 16; ++j) {
        int idx = base + j * 256 + t;
        if (idx < NE) {
            s[j] = ei[idx];
            d[j] = ei[NE + idx];
            rk[j] = atomicAdd(&h[d[j] >> 9], 1);
        } else d[j] = -1;
    }
    __syncthreads();
    for (int i = t; i < NBUCK; i += 256) {
        int c = h[i];
        if (c) lbase[i] = atomicAdd(&bcursor[i], c);
    }
    __syncthreads();
    #pragma unroll
    for (int j = 0; j < 16; ++j)
        if (d[j] >= 0) ebuf[lbase[d[j] >> 9] + rk[j]] = make_int2(s[j], d[j]);
}

// ---------- per-bucket degree histogram (LDS) + dinv ----------
__global__ __launch_bounds__(256) void k_bdeg(const int2* __restrict__ ebuf,
                                              const int* __restrict__ bstart,
                                              int* __restrict__ degi,
                                              float* __restrict__ dinv) {
    __shared__ int h[DPB];
    int b = blockIdx.x, t = threadIdx.x;
    for (int i = t; i < DPB; i += 256) h[i] = 0;
    __syncthreads();
    int d0 = b * DPB;
    int e0 = bstart[b], e1 = bstart[b + 1];
    for (int e = e0 + t; e < e1; e += 256) atomicAdd(&h[ebuf[e].y - d0], 1);
    __syncthreads();
    for (int i = t; i < DPB; i += 256) {
        int v = d0 + i;
        if (v < NV) {
            int dg = h[i];
            degi[v] = dg;
            dinv[v] = rsqrtf((float)dg + 1.0f);
        }
    }
}

// ---------- rowstart scan over deg (unchanged structure) ----------
__global__ void k_scan_chunk(const int* __restrict__ deg, int* __restrict__ rowstart,
                             int* __restrict__ bsums) {
    __shared__ int sdata[256];
    int t = threadIdx.x;
    int base = blockIdx.x * 1024 + t * 4;
    int vals[4];
    int s = 0;
    #pragma unroll
    for (int j = 0; j < 4; ++j) {
        int idx = base + j;
        int d = (idx < NV) ? deg[idx] : 0;
        vals[j] = s; s += d;
    }
    sdata[t] = s; __syncthreads();
    for (int off = 1; off < 256; off <<= 1) {
        int v = sdata[t];
        int add = (t >= off) ? sdata[t - off] : 0;
        __syncthreads();
        sdata[t] = v + add;
        __syncthreads();
    }
    int excl = (t == 0) ? 0 : sdata[t - 1];
    #pragma unroll
    for (int j = 0; j < 4; ++j) {
        int idx = base + j;
        if (idx < NV) rowstart[idx] = excl + vals[j];
    }
    if (t == 0) bsums[blockIdx.x] = sdata[255];
}

__global__ void k_scan_sums(int* bsums, int nchunks) {
    if (threadIdx.x == 0 && blockIdx.x == 0) {
        int run = 0;
        for (int i = 0; i < nchunks; ++i) { int v = bsums[i]; bsums[i] = run; run += v; }
    }
}

__global__ void k_scan_add(int* __restrict__ rowstart, const int* __restrict__ bsums) {
    int i = blockIdx.x * 256 + threadIdx.x;
    if (i < NV) rowstart[i] += bsums[i >> 10];
}

// ---------- per-bucket CSR fill: LDS cursors, L2-local scatter ----------
__global__ __launch_bounds__(256) void k_bfill(const int2* __restrict__ ebuf,
                                               const int* __restrict__ bstart,
                                               const int* __restrict__ rowstart,
                                               int* __restrict__ csr) {
    __shared__ int cur[DPB];
    int b = blockIdx.x, t = threadIdx.x, d0 = b * DPB;
    for (int i = t; i < DPB; i += 256) {
        int v = d0 + i;
        cur[i] = (v < NV) ? rowstart[v] : 0;
    }
    __syncthreads();
    int e0 = bstart[b], e1 = bstart[b + 1];
    for (int e = e0 + t; e < e1; e += 256) {
        int2 ed = ebuf[e];
        int slot = atomicAdd(&cur[ed.y - d0], 1);
        csr[slot] = ed.x;
    }
}

// ---------- input linear: Xb = bf16(vertices @ W_in + b_in) ----------
__global__ void k_in(const float* __restrict__ verts, const float* __restrict__ Win,
                     const float* __restrict__ bin, unsigned short* __restrict__ Xb) {
    int idx = blockIdx.x * 256 + threadIdx.x;
    if (idx >= NV * HD) return;
    int v = idx >> 7, c = idx & 127;
    float a = verts[v * 3 + 0], b = verts[v * 3 + 1], d = verts[v * 3 + 2];
    Xb[idx] = f2b(bin[c] + a * Win[c] + b * Win[128 + c] + d * Win[256 + c]);
}

// ---------- W [k][n] f32 -> Wt [n][k] bf16 ----------
__global__ void k_wt(const float* __restrict__ W, unsigned short* __restrict__ Wt) {
    int idx = blockIdx.x * 256 + threadIdx.x;
    if (idx >= HD * HD) return;
    int n = idx >> 7, k = idx & 127;
    Wt[n * HD + k] = f2b(W[k * HD + n]);
}

// ---------- H = X @ W  via MFMA bf16: 4 waves/block, 64 rows/block ----------
__global__ __launch_bounds__(256) void k_gemm_mfma(const unsigned short* __restrict__ Xb,
                                                   const unsigned short* __restrict__ Wt,
                                                   unsigned short* __restrict__ Hb) {
    int wave = threadIdx.x >> 6;
    int lane = threadIdx.x & 63;
    int r = lane & 15;
    int g = lane >> 4;                     // 0..3
    int row0 = blockIdx.x * 64 + wave * 16;
    int arow = row0 + r;
    bool valid = arow < NV;

    bf16x8 afrag[4];
    const unsigned short* xp = Xb + (size_t)arow * HD + g * 8;
    #pragma unroll
    for (int ks = 0; ks < 4; ++ks) {
        if (valid) afrag[ks] = *(const bf16x8*)(xp + ks * 32);
        else       afrag[ks] = bf16x8{0, 0, 0, 0, 0, 0, 0, 0};
    }

    #pragma unroll
    for (int nt = 0; nt < 8; ++nt) {
        f32x4 acc = {0.f, 0.f, 0.f, 0.f};
        const unsigned short* wp = Wt + (size_t)(nt * 16 + r) * HD + g * 8;
        #pragma unroll
        for (int ks = 0; ks < 4; ++ks) {
            bf16x8 bfrag = *(const bf16x8*)(wp + ks * 32);
            acc = __builtin_amdgcn_mfma_f32_16x16x32_bf16(afrag[ks], bfrag, acc, 0, 0, 0);
        }
        #pragma unroll
        for (int j = 0; j < 4; ++j) {
            int row = row0 + g * 4 + j;   // C/D: col = lane&15, row = (lane>>4)*4 + reg
            if (row < NV)
                Hb[(size_t)row * HD + nt * 16 + r] = f2b(acc[j]);
        }
    }
}

// ---------- aggregate: one wave per dst vertex, bf16 gather, f32 accum ----------
__global__ __launch_bounds__(256) void k_agg(const unsigned short* __restrict__ H,
                                             const float* __restrict__ dinv,
                                             const int* __restrict__ rowstart,
                                             const int* __restrict__ degi,
                                             const int* __restrict__ csr_src,
                                             const float* __restrict__ bias,
                                             unsigned short* __restrict__ Xo) {
    int gtid = blockIdx.x * 256 + threadIdx.x;
    int v = gtid >> 6;
    int lane = gtid & 63;
    if (v >= NV) return;
    float di = dinv[v];
    int rs = rowstart[v], len = degi[v];
    ushort2 hv = *(const ushort2*)(H + (size_t)v * HD + lane * 2);
    float sc = di * di;
    float a0 = b2f(hv.x) * sc, a1 = b2f(hv.y) * sc;
    int i = 0;
    for (; i + 1 < len; i += 2) {
        int s0 = csr_src[rs + i], s1 = csr_src[rs + i + 1];
        float w0 = dinv[s0] * di, w1 = dinv[s1] * di;
        ushort2 h0 = *(const ushort2*)(H + (size_t)s0 * HD + lane * 2);
        ushort2 h1 = *(const ushort2*)(H + (size_t)s1 * HD + lane * 2);
        a0 = fmaf(b2f(h0.x), w0, a0); a0 = fmaf(b2f(h1.x), w1, a0);
        a1 = fmaf(b2f(h0.y), w0, a1); a1 = fmaf(b2f(h1.y), w1, a1);
    }
    if (i < len) {
        int s0 = csr_src[rs + i];
        float w0 = dinv[s0] * di;
        ushort2 h0 = *(const ushort2*)(H + (size_t)s0 * HD + lane * 2);
        a0 = fmaf(b2f(h0.x), w0, a0);
        a1 = fmaf(b2f(h0.y), w0, a1);
    }
    float o0 = fmaxf(a0 + bias[lane * 2 + 0], 0.f);
    float o1 = fmaxf(a1 + bias[lane * 2 + 1], 0.f);
    ushort2 ov; ov.x = f2b(o0); ov.y = f2b(o1);
    *(ushort2*)(Xo + (size_t)v * HD + lane * 2) = ov;
}

// ---------- mean pool: 2048 blocks x 256 thr, register run-length accumulate ----------
__global__ __launch_bounds__(256) void k_pool(const unsigned short* __restrict__ X,
                                              const int* __restrict__ batch,
                                              float* __restrict__ pool,
                                              int* __restrict__ cnt) {
    constexpr int NCHUNK = 2048;
    constexpr int CHUNK = (NV + NCHUNK - 1) / NCHUNK;  // 49
    int c = threadIdx.x & 127;   // column
    int r = threadIdx.x >> 7;    // 0..1 vertex-row offset
    int v0 = blockIdx.x * CHUNK;
    if (v0 >= NV) return;
    int vend = min(v0 + CHUNK, NV);
    int cur = -1;
    float sum = 0.f;
    for (int v = v0 + r; v < vend; v += 2) {
        int bb = batch[v];
        if (bb != cur) {
            if (cur >= 0) atomicAdd(&pool[cur * HD + c], sum);
            cur = bb; sum = 0.f;
        }
        sum += b2f(X[(size_t)v * HD + c]);
    }
    if (cur >= 0) atomicAdd(&pool[cur * HD + c], sum);
    if (threadIdx.x == 0) {
        int prev = batch[v0]; int c0 = 0;
        for (int v = v0; v < vend; ++v) {
            int bb = batch[v];
            if (bb != prev) { atomicAdd(&cnt[prev], c0); prev = bb; c0 = 0; }
            ++c0;
        }
        atomicAdd(&cnt[prev], c0);
    }
}

// ---------- final linear + layernorm, one block per graph ----------
__global__ __launch_bounds__(256) void k_out(const float* __restrict__ pool,
                                             const int* __restrict__ cnt,
                                             const float* __restrict__ Wout,
                                             const float* __restrict__ bout,
                                             const float* __restrict__ gamma,
                                             const float* __restrict__ beta,
                                             float* __restrict__ out) {
    __shared__ float ps[HD];
    __shared__ float red[DM];
    int g = blockIdx.x, t = threadIdx.x;
    if (t < HD) {
        float cn = fmaxf((float)cnt[g], 1.0f);
        ps[t] = pool[g * HD + t] / cn;
    }
    __syncthreads();
    float acc = bout[t];
    #pragma unroll 8
    for (int k = 0; k < HD; ++k) acc = fmaf(ps[k], Wout[k * DM + t], acc);
    red[t] = acc; __syncthreads();
    for (int s2 = 128; s2 > 0; s2 >>= 1) {
        if (t < s2) red[t] += red[t + s2];
        __syncthreads();
    }
    float mu = red[0] * (1.0f / DM);
    __syncthreads();
    float d = acc - mu;
    red[t] = d * d; __syncthreads();
    for (int s2 = 128; s2 > 0; s2 >>= 1) {
        if (t < s2) red[t] += red[t + s2];
        __syncthreads();
    }
    float var = red[0] * (1.0f / DM);
    out[g * DM + t] = d * rsqrtf(var + EPSLN) * gamma[t] + beta[t];
}

extern "C" void kernel_launch(void* const* d_in, const int* in_sizes, int n_in,
                              void* d_out, int out_size, void* d_ws, size_t ws_size,
                              hipStream_t stream) {
    const float* verts = (const float*)d_in[0];
    const int*   ei    = (const int*)d_in[1];
    const int*   batch = (const int*)d_in[2];
    const float* Win   = (const float*)d_in[3];
    const float* bin   = (const float*)d_in[4];
    const float* W1    = (const float*)d_in[5];
    const float* b1    = (const float*)d_in[6];
    const float* W2    = (const float*)d_in[7];
    const float* b2    = (const float*)d_in[8];
    const float* W3    = (const float*)d_in[9];
    const float* b3    = (const float*)d_in[10];
    const float* Wout  = (const float*)d_in[11];
    const float* bout  = (const float*)d_in[12];
    const float* gamma = (const float*)d_in[13];
    const float* beta  = (const float*)d_in[14];
    float* out = (float*)d_out;

    char* wp = (char*)d_ws;
    auto alloc = [&](size_t bytes) -> char* {
        char* p = wp;
        wp += (bytes + 255) & ~(size_t)255;
        return p;
    };
    unsigned short* Xb  = (unsigned short*)alloc((size_t)NV * HD * 2);
    unsigned short* Hb  = (unsigned short*)alloc((size_t)NV * HD * 2);
    unsigned short* Wt  = (unsigned short*)alloc((size_t)HD * HD * 2);
    int*   degi     = (int*)alloc((size_t)NV * 4);
    float* dinv     = (float*)alloc((size_t)NV * 4);
    int*   rowstart = (int*)alloc((size_t)NV * 4);
    int*   csr      = (int*)alloc((size_t)NE * 4);
    int2*  ebuf     = (int2*)alloc((size_t)NE * 8);
    int*   bcount   = (int*)alloc((size_t)NBUCK * 4);
    int*   bstart   = (int*)alloc((size_t)(NBUCK + 1) * 4);
    int*   bcursor  = (int*)alloc((size_t)NBUCK * 4);
    float* pool     = (float*)alloc((size_t)NB * HD * 4);
    int*   cnt      = (int*)alloc((size_t)NB * 4);
    int*   bsums    = (int*)alloc(1024 * 4);

    hipMemsetAsync(bcount, 0, (size_t)NBUCK * 4, stream);
    hipMemsetAsync(pool,   0, (size_t)NB * HD * 4, stream);
    hipMemsetAsync(cnt,    0, (size_t)NB * 4, stream);

    // CSR build (bucketed, L2-local)
    k_bhist<<<NEB, 256, 0, stream>>>(ei, bcount);
    k_bscan<<<1, 64, 0, stream>>>(bcount, bstart, bcursor);
    k_bscatter<<<NEB, 256, 0, stream>>>(ei, bcursor, ebuf);
    k_bdeg<<<NBUCK, 256, 0, stream>>>(ebuf, bstart, degi, dinv);
    int nch = (NV + 1023) / 1024;
    k_scan_chunk<<<nch, 256, 0, stream>>>(degi, rowstart, bsums);
    k_scan_sums<<<1, 64, 0, stream>>>(bsums, nch);
    k_scan_add<<<(NV + 255) / 256, 256, 0, stream>>>(rowstart, bsums);
    k_bfill<<<NBUCK, 256, 0, stream>>>(ebuf, bstart, rowstart, csr);

    k_in<<<((size_t)NV * HD + 255) / 256, 256, 0, stream>>>(verts, Win, bin, Xb);

    const float* Wl[3] = {W1, W2, W3};
    const float* bl[3] = {b1, b2, b3};
    for (int l = 0; l < 3; ++l) {
        k_wt<<<(HD * HD + 255) / 256, 256, 0, stream>>>(Wl[l], Wt);
        k_gemm_mfma<<<(NV + 63) / 64, 256, 0, stream>>>(Xb, Wt, Hb);
        k_agg<<<((size_t)NV * 64 + 255) / 256, 256, 0, stream>>>(Hb, dinv, rowstart, degi, csr, bl[l], Xb);
    }

    k_pool<<<2048, 256, 0, stream>>>(Xb, batch, pool, cnt);
    k_out<<<NB, 256, 0, stream>>>(pool, cnt, Wout, bout, gamma, beta, out);
}

// Round 5
// 456.174 us; speedup vs baseline: 2.0678x; 1.2046x over previous
//
#include <hip/hip_runtime.h>

// Problem constants (match reference setup_inputs)
constexpr int NV = 100000;   // vertices
constexpr int NE = 1600000;  // directed edges
constexpr int NB = 64;       // graphs
constexpr int HD = 128;      // hidden
constexpr int DM = 256;      // out dim
#define EPSLN 1e-5f

// CSR bucketing
constexpr int DPB   = 512;                      // dsts per bucket
constexpr int NBUCK = (NV + DPB - 1) / DPB;     // 196
constexpr int EPB   = 4096;                     // edges per block (bucket kernels)
constexpr int NEB   = (NE + EPB - 1) / EPB;     // 391

typedef short bf16x8 __attribute__((ext_vector_type(8)));
typedef float f32x4 __attribute__((ext_vector_type(4)));

__device__ inline unsigned short f2b(float f) {
    union { float f; unsigned u; } x; x.f = f;
    unsigned r = x.u + 0x7FFF + ((x.u >> 16) & 1);
    return (unsigned short)(r >> 16);
}
__device__ inline float b2f(unsigned short h) {
    union { unsigned u; float f; } x; x.u = (unsigned)h << 16;
    return x.f;
}

// ---------- bucket histogram: count edges per dst-bucket ----------
__global__ __launch_bounds__(256) void k_bhist(const int* __restrict__ ei,
                                               int* __restrict__ bcount) {
    __shared__ int h[NBUCK];
    int t = threadIdx.x;
    for (int i = t; i < NBUCK; i += 256) h[i] = 0;
    __syncthreads();
    int base = blockIdx.x * EPB;
    #pragma unroll
    for (int j = 0; j < EPB / 256; ++j) {
        int idx = base + j * 256 + t;
        if (idx < NE) atomicAdd(&h[ei[NE + idx] >> 9], 1);
    }
    __syncthreads();
    for (int i = t; i < NBUCK; i += 256) if (h[i]) atomicAdd(&bcount[i], h[i]);
}

__global__ void k_bscan(const int* __restrict__ bcount, int* __restrict__ bstart,
                        int* __restrict__ bcursor) {
    if (threadIdx.x == 0 && blockIdx.x == 0) {
        int run = 0;
        for (int i = 0; i < NBUCK; ++i) { bstart[i] = run; bcursor[i] = run; run += bcount[i]; }
        bstart[NBUCK] = run;
    }
}

// ---------- scatter edges into bucket regions (coalesced runs) ----------
__global__ __launch_bounds__(256) void k_bscatter(const int* __restrict__ ei,
                                                  int* __restrict__ bcursor,
                                                  int2* __restrict__ ebuf) {
    __shared__ int h[NBUCK];
    __shared__ int lbase[NBUCK];
    int t = threadIdx.x;
    for (int i = t; i < NBUCK; i += 256) h[i] = 0;
    __syncthreads();
    int base = blockIdx.x * EPB;
    int s[16], d[16], rk[16];
    #pragma unroll
    for (int j = 0; j < 16; ++j) {
        int idx = base + j * 256 + t;
        if (idx < NE) {
            s[j] = ei[idx];
            d[j] = ei[NE + idx];
            rk[j] = atomicAdd(&h[d[j] >> 9], 1);
        } else d[j] = -1;
    }
    __syncthreads();
    for (int i = t; i < NBUCK; i += 256) {
        int c = h[i];
        if (c) lbase[i] = atomicAdd(&bcursor[i], c);
    }
    __syncthreads();
    #pragma unroll
    for (int j = 0; j < 16; ++j)
        if (d[j] >= 0) ebuf[lbase[d[j] >> 9] + rk[j]] = make_int2(s[j], d[j]);
}

// ---------- fused per-bucket: histogram -> local scan -> deg/dinv/rowstart -> CSR fill ----------
__global__ __launch_bounds__(256) void k_bcsr(const int2* __restrict__ ebuf,
                                              const int* __restrict__ bstart,
                                              int* __restrict__ degi,
                                              float* __restrict__ dinv,
                                              int* __restrict__ rowstart,
                                              int* __restrict__ csr) {
    __shared__ int h[DPB];
    __shared__ int sdata[256];
    int b = blockIdx.x, t = threadIdx.x, d0 = b * DPB;
    for (int i = t; i < DPB; i += 256) h[i] = 0;
    __syncthreads();
    int e0 = bstart[b], e1 = bstart[b + 1];
    for (int e = e0 + t; e < e1; e += 256) atomicAdd(&h[ebuf[e].y - d0], 1);
    __syncthreads();
    int a = h[2 * t], c = h[2 * t + 1];
    sdata[t] = a + c;
    __syncthreads();
    for (int off = 1; off < 256; off <<= 1) {
        int v = sdata[t];
        int add = (t >= off) ? sdata[t - off] : 0;
        __syncthreads();
        sdata[t] = v + add;
        __syncthreads();
    }
    int excl = (t == 0) ? 0 : sdata[t - 1];
    int base = bstart[b];
    int v0 = d0 + 2 * t, v1 = v0 + 1;
    if (v0 < NV) { rowstart[v0] = base + excl;     degi[v0] = a; dinv[v0] = rsqrtf((float)a + 1.0f); }
    if (v1 < NV) { rowstart[v1] = base + excl + a; degi[v1] = c; dinv[v1] = rsqrtf((float)c + 1.0f); }
    // reuse h as cursors (all histogram reads are in registers now)
    h[2 * t]     = base + excl;
    h[2 * t + 1] = base + excl + a;
    __syncthreads();
    for (int e = e0 + t; e < e1; e += 256) {
        int2 ed = ebuf[e];
        int slot = atomicAdd(&h[ed.y - d0], 1);
        csr[slot] = ed.x;
    }
}

// ---------- input linear: Xb = bf16(vertices @ W_in + b_in) ----------
__global__ void k_in(const float* __restrict__ verts, const float* __restrict__ Win,
                     const float* __restrict__ bin, unsigned short* __restrict__ Xb) {
    int idx = blockIdx.x * 256 + threadIdx.x;
    if (idx >= NV * HD) return;
    int v = idx >> 7, c = idx & 127;
    float a = verts[v * 3 + 0], b = verts[v * 3 + 1], d = verts[v * 3 + 2];
    Xb[idx] = f2b(bin[c] + a * Win[c] + b * Win[128 + c] + d * Win[256 + c]);
}

// ---------- all 3 layer weights: W [k][n] f32 -> Wt [l][n][k] bf16 ----------
__global__ void k_wt3(const float* __restrict__ W1, const float* __restrict__ W2,
                      const float* __restrict__ W3, unsigned short* __restrict__ Wt) {
    int idx = blockIdx.x * 256 + threadIdx.x;
    if (idx >= 3 * HD * HD) return;
    int l = idx >> 14, r = idx & 16383;
    const float* W = (l == 0) ? W1 : ((l == 1) ? W2 : W3);
    int n = r >> 7, k = r & 127;
    Wt[idx - r + n * HD + k] = f2b(W[k * HD + n]);
}

// ---------- H = X @ W  via MFMA bf16: 4 waves/block, 64 rows/block ----------
__global__ __launch_bounds__(256) void k_gemm_mfma(const unsigned short* __restrict__ Xb,
                                                   const unsigned short* __restrict__ Wt,
                                                   unsigned short* __restrict__ Hb) {
    int wave = threadIdx.x >> 6;
    int lane = threadIdx.x & 63;
    int r = lane & 15;
    int g = lane >> 4;                     // 0..3
    int row0 = blockIdx.x * 64 + wave * 16;
    int arow = row0 + r;
    bool valid = arow < NV;

    bf16x8 afrag[4];
    const unsigned short* xp = Xb + (size_t)arow * HD + g * 8;
    #pragma unroll
    for (int ks = 0; ks < 4; ++ks) {
        if (valid) afrag[ks] = *(const bf16x8*)(xp + ks * 32);
        else       afrag[ks] = bf16x8{0, 0, 0, 0, 0, 0, 0, 0};
    }

    #pragma unroll
    for (int nt = 0; nt < 8; ++nt) {
        f32x4 acc = {0.f, 0.f, 0.f, 0.f};
        const unsigned short* wp = Wt + (size_t)(nt * 16 + r) * HD + g * 8;
        #pragma unroll
        for (int ks = 0; ks < 4; ++ks) {
            bf16x8 bfrag = *(const bf16x8*)(wp + ks * 32);
            acc = __builtin_amdgcn_mfma_f32_16x16x32_bf16(afrag[ks], bfrag, acc, 0, 0, 0);
        }
        #pragma unroll
        for (int j = 0; j < 4; ++j) {
            int row = row0 + g * 4 + j;   // C/D: col = lane&15, row = (lane>>4)*4 + reg
            if (row < NV)
                Hb[(size_t)row * HD + nt * 16 + r] = f2b(acc[j]);
        }
    }
}

// ---------- aggregate: one wave per dst, half-waves process even/odd edges ----------
__global__ __launch_bounds__(256) void k_agg(const unsigned short* __restrict__ H,
                                             const float* __restrict__ dinv,
                                             const int* __restrict__ rowstart,
                                             const int* __restrict__ degi,
                                             const int* __restrict__ csr_src,
                                             const float* __restrict__ bias,
                                             unsigned short* __restrict__ Xo) {
    int gtid = blockIdx.x * 256 + threadIdx.x;
    int v = gtid >> 6;
    if (v >= NV) return;
    int lane = threadIdx.x & 63;
    int half = lane >> 5;     // 0: even edges, 1: odd edges
    int l5 = lane & 31;       // col group: cols l5*4 .. l5*4+3
    float di = dinv[v];
    int rs = rowstart[v], len = degi[v];
    float sc = di * di;
    ushort4 hv = *(const ushort4*)(H + (size_t)v * HD + l5 * 4);
    float a0, a1, a2, a3;
    if (half == 0) {
        a0 = b2f(hv.x) * sc; a1 = b2f(hv.y) * sc;
        a2 = b2f(hv.z) * sc; a3 = b2f(hv.w) * sc;
    } else {
        a0 = a1 = a2 = a3 = 0.f;
    }
    int cnt = (len - half + 1) >> 1;   // edges this half handles
    int idx = rs + half;
    int j = 0;
    for (; j + 1 < cnt; j += 2) {
        int s0 = csr_src[idx], s1 = csr_src[idx + 2];
        idx += 4;
        float w0 = dinv[s0] * di, w1 = dinv[s1] * di;
        ushort4 h0 = *(const ushort4*)(H + (size_t)s0 * HD + l5 * 4);
        ushort4 h1 = *(const ushort4*)(H + (size_t)s1 * HD + l5 * 4);
        a0 = fmaf(b2f(h0.x), w0, a0); a0 = fmaf(b2f(h1.x), w1, a0);
        a1 = fmaf(b2f(h0.y), w0, a1); a1 = fmaf(b2f(h1.y), w1, a1);
        a2 = fmaf(b2f(h0.z), w0, a2); a2 = fmaf(b2f(h1.z), w1, a2);
        a3 = fmaf(b2f(h0.w), w0, a3); a3 = fmaf(b2f(h1.w), w1, a3);
    }
    if (j < cnt) {
        int s0 = csr_src[idx];
        float w0 = dinv[s0] * di;
        ushort4 h0 = *(const ushort4*)(H + (size_t)s0 * HD + l5 * 4);
        a0 = fmaf(b2f(h0.x), w0, a0);
        a1 = fmaf(b2f(h0.y), w0, a1);
        a2 = fmaf(b2f(h0.z), w0, a2);
        a3 = fmaf(b2f(h0.w), w0, a3);
    }
    // cross-half reduce
    a0 += __shfl_xor(a0, 32);
    a1 += __shfl_xor(a1, 32);
    a2 += __shfl_xor(a2, 32);
    a3 += __shfl_xor(a3, 32);
    if (half == 0) {
        float4 b4 = *(const float4*)(bias + l5 * 4);
        ushort4 ov;
        ov.x = f2b(fmaxf(a0 + b4.x, 0.f));
        ov.y = f2b(fmaxf(a1 + b4.y, 0.f));
        ov.z = f2b(fmaxf(a2 + b4.z, 0.f));
        ov.w = f2b(fmaxf(a3 + b4.w, 0.f));
        *(ushort4*)(Xo + (size_t)v * HD + l5 * 4) = ov;
    }
}

// ---------- mean pool: 2048 blocks x 256 thr, register run-length accumulate ----------
__global__ __launch_bounds__(256) void k_pool(const unsigned short* __restrict__ X,
                                              const int* __restrict__ batch,
                                              float* __restrict__ pool,
                                              int* __restrict__ cnt) {
    constexpr int NCHUNK = 2048;
    constexpr int CHUNK = (NV + NCHUNK - 1) / NCHUNK;  // 49
    int c = threadIdx.x & 127;   // column
    int r = threadIdx.x >> 7;    // 0..1 vertex-row offset
    int v0 = blockIdx.x * CHUNK;
    if (v0 >= NV) return;
    int vend = min(v0 + CHUNK, NV);
    int cur = -1;
    float sum = 0.f;
    for (int v = v0 + r; v < vend; v += 2) {
        int bb = batch[v];
        if (bb != cur) {
            if (cur >= 0) atomicAdd(&pool[cur * HD + c], sum);
            cur = bb; sum = 0.f;
        }
        sum += b2f(X[(size_t)v * HD + c]);
    }
    if (cur >= 0) atomicAdd(&pool[cur * HD + c], sum);
    if (threadIdx.x == 0) {
        int prev = batch[v0]; int c0 = 0;
        for (int v = v0; v < vend; ++v) {
            int bb = batch[v];
            if (bb != prev) { atomicAdd(&cnt[prev], c0); prev = bb; c0 = 0; }
            ++c0;
        }
        atomicAdd(&cnt[prev], c0);
    }
}

// ---------- final linear + layernorm, one block per graph ----------
__global__ __launch_bounds__(256) void k_out(const float* __restrict__ pool,
                                             const int* __restrict__ cnt,
                                             const float* __restrict__ Wout,
                                             const float* __restrict__ bout,
                                             const float* __restrict__ gamma,
                                             const float* __restrict__ beta,
                                             float* __restrict__ out) {
    __shared__ float ps[HD];
    __shared__ float red[DM];
    int g = blockIdx.x, t = threadIdx.x;
    if (t < HD) {
        float cn = fmaxf((float)cnt[g], 1.0f);
        ps[t] = pool[g * HD + t] / cn;
    }
    __syncthreads();
    float acc = bout[t];
    #pragma unroll 8
    for (int k = 0; k < HD; ++k) acc = fmaf(ps[k], Wout[k * DM + t], acc);
    red[t] = acc; __syncthreads();
    for (int s2 = 128; s2 > 0; s2 >>= 1) {
        if (t < s2) red[t] += red[t + s2];
        __syncthreads();
    }
    float mu = red[0] * (1.0f / DM);
    __syncthreads();
    float d = acc - mu;
    red[t] = d * d; __syncthreads();
    for (int s2 = 128; s2 > 0; s2 >>= 1) {
        if (t < s2) red[t] += red[t + s2];
        __syncthreads();
    }
    float var = red[0] * (1.0f / DM);
    out[g * DM + t] = d * rsqrtf(var + EPSLN) * gamma[t] + beta[t];
}

extern "C" void kernel_launch(void* const* d_in, const int* in_sizes, int n_in,
                              void* d_out, int out_size, void* d_ws, size_t ws_size,
                              hipStream_t stream) {
    const float* verts = (const float*)d_in[0];
    const int*   ei    = (const int*)d_in[1];
    const int*   batch = (const int*)d_in[2];
    const float* Win   = (const float*)d_in[3];
    const float* bin   = (const float*)d_in[4];
    const float* W1    = (const float*)d_in[5];
    const float* b1    = (const float*)d_in[6];
    const float* W2    = (const float*)d_in[7];
    const float* b2    = (const float*)d_in[8];
    const float* W3    = (const float*)d_in[9];
    const float* b3    = (const float*)d_in[10];
    const float* Wout  = (const float*)d_in[11];
    const float* bout  = (const float*)d_in[12];
    const float* gamma = (const float*)d_in[13];
    const float* beta  = (const float*)d_in[14];
    float* out = (float*)d_out;

    char* wp = (char*)d_ws;
    auto alloc = [&](size_t bytes) -> char* {
        char* p = wp;
        wp += (bytes + 255) & ~(size_t)255;
        return p;
    };
    unsigned short* Xb  = (unsigned short*)alloc((size_t)NV * HD * 2);
    unsigned short* Hb  = (unsigned short*)alloc((size_t)NV * HD * 2);
    unsigned short* Wt  = (unsigned short*)alloc((size_t)3 * HD * HD * 2);
    int*   degi     = (int*)alloc((size_t)NV * 4);
    float* dinv     = (float*)alloc((size_t)NV * 4);
    int*   rowstart = (int*)alloc((size_t)NV * 4);
    int*   csr      = (int*)alloc((size_t)NE * 4);
    int2*  ebuf     = (int2*)alloc((size_t)NE * 8);
    int*   bcount   = (int*)alloc((size_t)NBUCK * 4);
    int*   bstart   = (int*)alloc((size_t)(NBUCK + 1) * 4);
    int*   bcursor  = (int*)alloc((size_t)NBUCK * 4);
    float* pool     = (float*)alloc((size_t)NB * HD * 4);
    int*   cnt      = (int*)alloc((size_t)NB * 4);

    hipMemsetAsync(bcount, 0, (size_t)NBUCK * 4, stream);
    hipMemsetAsync(pool,   0, (size_t)NB * HD * 4, stream);
    hipMemsetAsync(cnt,    0, (size_t)NB * 4, stream);

    // CSR build (bucketed, L2-local)
    k_bhist<<<NEB, 256, 0, stream>>>(ei, bcount);
    k_bscan<<<1, 64, 0, stream>>>(bcount, bstart, bcursor);
    k_bscatter<<<NEB, 256, 0, stream>>>(ei, bcursor, ebuf);
    k_bcsr<<<NBUCK, 256, 0, stream>>>(ebuf, bstart, degi, dinv, rowstart, csr);

    k_in<<<((size_t)NV * HD + 255) / 256, 256, 0, stream>>>(verts, Win, bin, Xb);
    k_wt3<<<(3 * HD * HD + 255) / 256, 256, 0, stream>>>(W1, W2, W3, Wt);

    const float* bl[3] = {b1, b2, b3};
    for (int l = 0; l < 3; ++l) {
        k_gemm_mfma<<<(NV + 63) / 64, 256, 0, stream>>>(Xb, Wt + (size_t)l * HD * HD, Hb);
        k_agg<<<((size_t)NV * 64 + 255) / 256, 256, 0, stream>>>(Hb, dinv, rowstart, degi, csr, bl[l], Xb);
    }

    k_pool<<<2048, 256, 0, stream>>>(Xb, batch, pool, cnt);
    k_out<<<NB, 256, 0, stream>>>(pool, cnt, Wout, bout, gamma, beta, out);
}

// Round 6
// 398.589 us; speedup vs baseline: 2.3665x; 1.1445x over previous
//
#include <hip/hip_runtime.h>

// Problem constants (match reference setup_inputs)
constexpr int NV = 100000;   // vertices
constexpr int NE = 1600000;  // directed edges
constexpr int NB = 64;       // graphs
constexpr int HD = 128;      // hidden
constexpr int DM = 256;      // out dim
#define EPSLN 1e-5f

// CSR bucketing
constexpr int DPB   = 512;                      // dsts per bucket
constexpr int NBUCK = (NV + DPB - 1) / DPB;     // 196
constexpr int EPB   = 4096;                     // edges per block (bucket kernels)
constexpr int NEB   = (NE + EPB - 1) / EPB;     // 391

typedef short bf16x8 __attribute__((ext_vector_type(8)));
typedef float f32x4 __attribute__((ext_vector_type(4)));

__device__ inline unsigned short f2b(float f) {
    union { float f; unsigned u; } x; x.f = f;
    unsigned r = x.u + 0x7FFF + ((x.u >> 16) & 1);
    return (unsigned short)(r >> 16);
}
__device__ inline float b2f(unsigned short h) {
    union { unsigned u; float f; } x; x.u = (unsigned)h << 16;
    return x.f;
}

// ---------- bucket histogram: count edges per dst-bucket ----------
__global__ __launch_bounds__(256) void k_bhist(const int* __restrict__ ei,
                                               int* __restrict__ bcount) {
    __shared__ int h[NBUCK];
    int t = threadIdx.x;
    for (int i = t; i < NBUCK; i += 256) h[i] = 0;
    __syncthreads();
    int base = blockIdx.x * EPB;
    #pragma unroll
    for (int j = 0; j < EPB / 256; ++j) {
        int idx = base + j * 256 + t;
        if (idx < NE) atomicAdd(&h[ei[NE + idx] >> 9], 1);
    }
    __syncthreads();
    for (int i = t; i < NBUCK; i += 256) if (h[i]) atomicAdd(&bcount[i], h[i]);
}

__global__ void k_bscan(const int* __restrict__ bcount, int* __restrict__ bstart,
                        int* __restrict__ bcursor) {
    if (threadIdx.x == 0 && blockIdx.x == 0) {
        int run = 0;
        for (int i = 0; i < NBUCK; ++i) { bstart[i] = run; bcursor[i] = run; run += bcount[i]; }
        bstart[NBUCK] = run;
    }
}

// ---------- scatter edges into bucket regions (coalesced runs) ----------
__global__ __launch_bounds__(256) void k_bscatter(const int* __restrict__ ei,
                                                  int* __restrict__ bcursor,
                                                  int2* __restrict__ ebuf) {
    __shared__ int h[NBUCK];
    __shared__ int lbase[NBUCK];
    int t = threadIdx.x;
    for (int i = t; i < NBUCK; i += 256) h[i] = 0;
    __syncthreads();
    int base = blockIdx.x * EPB;
    int s[16], d[16], rk[16];
    #pragma unroll
    for (int j = 0; j < 16; ++j) {
        int idx = base + j * 256 + t;
        if (idx < NE) {
            s[j] = ei[idx];
            d[j] = ei[NE + idx];
            rk[j] = atomicAdd(&h[d[j] >> 9], 1);
        } else d[j] = -1;
    }
    __syncthreads();
    for (int i = t; i < NBUCK; i += 256) {
        int c = h[i];
        if (c) lbase[i] = atomicAdd(&bcursor[i], c);
    }
    __syncthreads();
    #pragma unroll
    for (int j = 0; j < 16; ++j)
        if (d[j] >= 0) ebuf[lbase[d[j] >> 9] + rk[j]] = make_int2(s[j], d[j]);
}

// ---------- fused per-bucket: histogram -> local scan -> deg/dinv/rowstart -> CSR fill ----------
__global__ __launch_bounds__(256) void k_bcsr(const int2* __restrict__ ebuf,
                                              const int* __restrict__ bstart,
                                              int* __restrict__ degi,
                                              float* __restrict__ dinv,
                                              int* __restrict__ rowstart,
                                              int* __restrict__ csr) {
    __shared__ int h[DPB];
    __shared__ int sdata[256];
    int b = blockIdx.x, t = threadIdx.x, d0 = b * DPB;
    for (int i = t; i < DPB; i += 256) h[i] = 0;
    __syncthreads();
    int e0 = bstart[b], e1 = bstart[b + 1];
    for (int e = e0 + t; e < e1; e += 256) atomicAdd(&h[ebuf[e].y - d0], 1);
    __syncthreads();
    int a = h[2 * t], c = h[2 * t + 1];
    sdata[t] = a + c;
    __syncthreads();
    for (int off = 1; off < 256; off <<= 1) {
        int v = sdata[t];
        int add = (t >= off) ? sdata[t - off] : 0;
        __syncthreads();
        sdata[t] = v + add;
        __syncthreads();
    }
    int excl = (t == 0) ? 0 : sdata[t - 1];
    int base = bstart[b];
    int v0 = d0 + 2 * t, v1 = v0 + 1;
    if (v0 < NV) { rowstart[v0] = base + excl;     degi[v0] = a; dinv[v0] = rsqrtf((float)a + 1.0f); }
    if (v1 < NV) { rowstart[v1] = base + excl + a; degi[v1] = c; dinv[v1] = rsqrtf((float)c + 1.0f); }
    // reuse h as cursors (all histogram reads are in registers now)
    h[2 * t]     = base + excl;
    h[2 * t + 1] = base + excl + a;
    __syncthreads();
    for (int e = e0 + t; e < e1; e += 256) {
        int2 ed = ebuf[e];
        int slot = atomicAdd(&h[ed.y - d0], 1);
        csr[slot] = ed.x;
    }
}

// ---------- fold layer-1: Wc = Win @ W1 (3x128), bc = bin @ W1 (128) ----------
__global__ void k_wc(const float* __restrict__ Win, const float* __restrict__ bin,
                     const float* __restrict__ W1, float* __restrict__ Wc,
                     float* __restrict__ bc) {
    int c = threadIdx.x;
    float w0 = 0.f, w1 = 0.f, w2 = 0.f, bv = 0.f;
    for (int k = 0; k < HD; ++k) {
        float w = W1[k * HD + c];
        w0 = fmaf(Win[k], w, w0);
        w1 = fmaf(Win[128 + k], w, w1);
        w2 = fmaf(Win[256 + k], w, w2);
        bv = fmaf(bin[k], w, bv);
    }
    Wc[c] = w0; Wc[128 + c] = w1; Wc[256 + c] = w2; bc[c] = bv;
}

// ---------- layer-1 H directly from vertices (f32 throughout) ----------
__global__ void k_h1(const float* __restrict__ verts, const float* __restrict__ Wc,
                     const float* __restrict__ bc, unsigned short* __restrict__ Hb) {
    int idx = blockIdx.x * 256 + threadIdx.x;
    if (idx >= NV * HD) return;
    int v = idx >> 7, c = idx & 127;
    float a = verts[v * 3 + 0], b = verts[v * 3 + 1], d = verts[v * 3 + 2];
    Hb[idx] = f2b(bc[c] + a * Wc[c] + b * Wc[128 + c] + d * Wc[256 + c]);
}

// ---------- W2,W3 [k][n] f32 -> Wt [l][n][k] bf16 ----------
__global__ void k_wt2(const float* __restrict__ W2, const float* __restrict__ W3,
                      unsigned short* __restrict__ Wt) {
    int idx = blockIdx.x * 256 + threadIdx.x;
    if (idx >= 2 * HD * HD) return;
    int l = idx >> 14, r = idx & 16383;
    const float* W = (l == 0) ? W2 : W3;
    int n = r >> 7, k = r & 127;
    Wt[idx - r + n * HD + k] = f2b(W[k * HD + n]);
}

// ---------- H = X @ W  via MFMA bf16: 4 waves/block, 64 rows/block ----------
__global__ __launch_bounds__(256) void k_gemm_mfma(const unsigned short* __restrict__ Xb,
                                                   const unsigned short* __restrict__ Wt,
                                                   unsigned short* __restrict__ Hb) {
    int wave = threadIdx.x >> 6;
    int lane = threadIdx.x & 63;
    int r = lane & 15;
    int g = lane >> 4;                     // 0..3
    int row0 = blockIdx.x * 64 + wave * 16;
    int arow = row0 + r;
    bool valid = arow < NV;

    bf16x8 afrag[4];
    const unsigned short* xp = Xb + (size_t)arow * HD + g * 8;
    #pragma unroll
    for (int ks = 0; ks < 4; ++ks) {
        if (valid) afrag[ks] = *(const bf16x8*)(xp + ks * 32);
        else       afrag[ks] = bf16x8{0, 0, 0, 0, 0, 0, 0, 0};
    }

    #pragma unroll
    for (int nt = 0; nt < 8; ++nt) {
        f32x4 acc = {0.f, 0.f, 0.f, 0.f};
        const unsigned short* wp = Wt + (size_t)(nt * 16 + r) * HD + g * 8;
        #pragma unroll
        for (int ks = 0; ks < 4; ++ks) {
            bf16x8 bfrag = *(const bf16x8*)(wp + ks * 32);
            acc = __builtin_amdgcn_mfma_f32_16x16x32_bf16(afrag[ks], bfrag, acc, 0, 0, 0);
        }
        #pragma unroll
        for (int j = 0; j < 4; ++j) {
            int row = row0 + g * 4 + j;   // C/D: col = lane&15, row = (lane>>4)*4 + reg
            if (row < NV)
                Hb[(size_t)row * HD + nt * 16 + r] = f2b(acc[j]);
        }
    }
}

// ---------- aggregate: one wave per dst, quarter-waves over edges, bf16x8 rows ----------
__global__ __launch_bounds__(256) void k_agg(const unsigned short* __restrict__ H,
                                             const float* __restrict__ dinv,
                                             const int* __restrict__ rowstart,
                                             const int* __restrict__ degi,
                                             const int* __restrict__ csr_src,
                                             const float* __restrict__ bias,
                                             unsigned short* __restrict__ Xo) {
    int gtid = blockIdx.x * 256 + threadIdx.x;
    int v = gtid >> 6;
    if (v >= NV) return;
    int lane = threadIdx.x & 63;
    int q = lane >> 4;        // quarter 0..3: edges q, q+4, q+8, ...
    int l4 = lane & 15;       // col group: cols l4*8 .. l4*8+7
    float di = dinv[v];
    int rs = rowstart[v], len = degi[v];
    float a[8];
    if (q == 0) {
        float sc = di * di;
        bf16x8 hv = *(const bf16x8*)(H + (size_t)v * HD + l4 * 8);
        #pragma unroll
        for (int jj = 0; jj < 8; ++jj) a[jj] = b2f((unsigned short)hv[jj]) * sc;
    } else {
        #pragma unroll
        for (int jj = 0; jj < 8; ++jj) a[jj] = 0.f;
    }
    int cnt = (len - q + 3) >> 2;   // edges this quarter handles
    int idx = rs + q;
    int j = 0;
    for (; j + 1 < cnt; j += 2) {
        int s0 = csr_src[idx], s1 = csr_src[idx + 4];
        idx += 8;
        float w0 = dinv[s0] * di, w1 = dinv[s1] * di;
        bf16x8 h0 = *(const bf16x8*)(H + (size_t)s0 * HD + l4 * 8);
        bf16x8 h1 = *(const bf16x8*)(H + (size_t)s1 * HD + l4 * 8);
        #pragma unroll
        for (int jj = 0; jj < 8; ++jj) {
            a[jj] = fmaf(b2f((unsigned short)h0[jj]), w0, a[jj]);
            a[jj] = fmaf(b2f((unsigned short)h1[jj]), w1, a[jj]);
        }
    }
    if (j < cnt) {
        int s0 = csr_src[idx];
        float w0 = dinv[s0] * di;
        bf16x8 h0 = *(const bf16x8*)(H + (size_t)s0 * HD + l4 * 8);
        #pragma unroll
        for (int jj = 0; jj < 8; ++jj)
            a[jj] = fmaf(b2f((unsigned short)h0[jj]), w0, a[jj]);
    }
    // reduce across quarters (lanes l4, l4+16, l4+32, l4+48)
    #pragma unroll
    for (int jj = 0; jj < 8; ++jj) {
        a[jj] += __shfl_xor(a[jj], 16);
        a[jj] += __shfl_xor(a[jj], 32);
    }
    if (q == 0) {
        bf16x8 ov;
        #pragma unroll
        for (int jj = 0; jj < 8; ++jj)
            ov[jj] = (short)f2b(fmaxf(a[jj] + bias[l4 * 8 + jj], 0.f));
        *(bf16x8*)(Xo + (size_t)v * HD + l4 * 8) = ov;
    }
}

// ---------- mean pool: 2048 blocks x 256 thr, register run-length accumulate ----------
__global__ __launch_bounds__(256) void k_pool(const unsigned short* __restrict__ X,
                                              const int* __restrict__ batch,
                                              float* __restrict__ pool,
                                              int* __restrict__ cnt) {
    constexpr int NCHUNK = 2048;
    constexpr int CHUNK = (NV + NCHUNK - 1) / NCHUNK;  // 49
    int c = threadIdx.x & 127;   // column
    int r = threadIdx.x >> 7;    // 0..1 vertex-row offset
    int v0 = blockIdx.x * CHUNK;
    if (v0 >= NV) return;
    int vend = min(v0 + CHUNK, NV);
    int cur = -1;
    float sum = 0.f;
    for (int v = v0 + r; v < vend; v += 2) {
        int bb = batch[v];
        if (bb != cur) {
            if (cur >= 0) atomicAdd(&pool[cur * HD + c], sum);
            cur = bb; sum = 0.f;
        }
        sum += b2f(X[(size_t)v * HD + c]);
    }
    if (cur >= 0) atomicAdd(&pool[cur * HD + c], sum);
    if (threadIdx.x == 0) {
        int prev = batch[v0]; int c0 = 0;
        for (int v = v0; v < vend; ++v) {
            int bb = batch[v];
            if (bb != prev) { atomicAdd(&cnt[prev], c0); prev = bb; c0 = 0; }
            ++c0;
        }
        atomicAdd(&cnt[prev], c0);
    }
}

// ---------- final linear + layernorm, one block per graph ----------
__global__ __launch_bounds__(256) void k_out(const float* __restrict__ pool,
                                             const int* __restrict__ cnt,
                                             const float* __restrict__ Wout,
                                             const float* __restrict__ bout,
                                             const float* __restrict__ gamma,
                                             const float* __restrict__ beta,
                                             float* __restrict__ out) {
    __shared__ float ps[HD];
    __shared__ float red[DM];
    int g = blockIdx.x, t = threadIdx.x;
    if (t < HD) {
        float cn = fmaxf((float)cnt[g], 1.0f);
        ps[t] = pool[g * HD + t] / cn;
    }
    __syncthreads();
    float acc = bout[t];
    #pragma unroll 8
    for (int k = 0; k < HD; ++k) acc = fmaf(ps[k], Wout[k * DM + t], acc);
    red[t] = acc; __syncthreads();
    for (int s2 = 128; s2 > 0; s2 >>= 1) {
        if (t < s2) red[t] += red[t + s2];
        __syncthreads();
    }
    float mu = red[0] * (1.0f / DM);
    __syncthreads();
    float d = acc - mu;
    red[t] = d * d; __syncthreads();
    for (int s2 = 128; s2 > 0; s2 >>= 1) {
        if (t < s2) red[t] += red[t + s2];
        __syncthreads();
    }
    float var = red[0] * (1.0f / DM);
    out[g * DM + t] = d * rsqrtf(var + EPSLN) * gamma[t] + beta[t];
}

extern "C" void kernel_launch(void* const* d_in, const int* in_sizes, int n_in,
                              void* d_out, int out_size, void* d_ws, size_t ws_size,
                              hipStream_t stream) {
    const float* verts = (const float*)d_in[0];
    const int*   ei    = (const int*)d_in[1];
    const int*   batch = (const int*)d_in[2];
    const float* Win   = (const float*)d_in[3];
    const float* bin   = (const float*)d_in[4];
    const float* W1    = (const float*)d_in[5];
    const float* b1    = (const float*)d_in[6];
    const float* W2    = (const float*)d_in[7];
    const float* b2    = (const float*)d_in[8];
    const float* W3    = (const float*)d_in[9];
    const float* b3    = (const float*)d_in[10];
    const float* Wout  = (const float*)d_in[11];
    const float* bout  = (const float*)d_in[12];
    const float* gamma = (const float*)d_in[13];
    const float* beta  = (const float*)d_in[14];
    float* out = (float*)d_out;

    char* wp = (char*)d_ws;
    auto alloc = [&](size_t bytes) -> char* {
        char* p = wp;
        wp += (bytes + 255) & ~(size_t)255;
        return p;
    };
    unsigned short* Xb  = (unsigned short*)alloc((size_t)NV * HD * 2);
    unsigned short* Hb  = (unsigned short*)alloc((size_t)NV * HD * 2);
    unsigned short* Wt  = (unsigned short*)alloc((size_t)2 * HD * HD * 2);
    float* Wc       = (float*)alloc((size_t)3 * HD * 4);
    float* bc       = (float*)alloc((size_t)HD * 4);
    int*   degi     = (int*)alloc((size_t)NV * 4);
    float* dinv     = (float*)alloc((size_t)NV * 4);
    int*   rowstart = (int*)alloc((size_t)NV * 4);
    int*   csr      = (int*)alloc((size_t)NE * 4);
    int2*  ebuf     = (int2*)alloc((size_t)NE * 8);
    int*   bcount   = (int*)alloc((size_t)NBUCK * 4);
    int*   bstart   = (int*)alloc((size_t)(NBUCK + 1) * 4);
    int*   bcursor  = (int*)alloc((size_t)NBUCK * 4);
    float* pool     = (float*)alloc((size_t)NB * HD * 4);
    int*   cnt      = (int*)alloc((size_t)NB * 4);

    hipMemsetAsync(bcount, 0, (size_t)NBUCK * 4, stream);
    hipMemsetAsync(pool,   0, (size_t)NB * HD * 4, stream);
    hipMemsetAsync(cnt,    0, (size_t)NB * 4, stream);

    // CSR build (bucketed, L2-local)
    k_bhist<<<NEB, 256, 0, stream>>>(ei, bcount);
    k_bscan<<<1, 64, 0, stream>>>(bcount, bstart, bcursor);
    k_bscatter<<<NEB, 256, 0, stream>>>(ei, bcursor, ebuf);
    k_bcsr<<<NBUCK, 256, 0, stream>>>(ebuf, bstart, degi, dinv, rowstart, csr);

    // weights prep + layer-1 H (GEMM folded into 3-wide affine)
    k_wc<<<1, 128, 0, stream>>>(Win, bin, W1, Wc, bc);
    k_wt2<<<(2 * HD * HD + 255) / 256, 256, 0, stream>>>(W2, W3, Wt);
    k_h1<<<((size_t)NV * HD + 255) / 256, 256, 0, stream>>>(verts, Wc, bc, Hb);

    // layer 1 aggregate
    k_agg<<<((size_t)NV * 64 + 255) / 256, 256, 0, stream>>>(Hb, dinv, rowstart, degi, csr, b1, Xb);
    // layers 2,3
    const float* bl[2] = {b2, b3};
    for (int l = 0; l < 2; ++l) {
        k_gemm_mfma<<<(NV + 63) / 64, 256, 0, stream>>>(Xb, Wt + (size_t)l * HD * HD, Hb);
        k_agg<<<((size_t)NV * 64 + 255) / 256, 256, 0, stream>>>(Hb, dinv, rowstart, degi, csr, bl[l], Xb);
    }

    k_pool<<<2048, 256, 0, stream>>>(Xb, batch, pool, cnt);
    k_out<<<NB, 256, 0, stream>>>(pool, cnt, Wout, bout, gamma, beta, out);
}